// Round 1
// baseline (114.880 us; speedup 1.0000x reference)
//
#include <hip/hip_runtime.h>
#include <hip/hip_bf16.h>

typedef __attribute__((ext_vector_type(8))) short bf16x8;
typedef __attribute__((ext_vector_type(4))) float f32x4;

#define NB 4096
#define ND 512
#define MARGIN_F 0.2f

// order-preserving float -> uint encoding for atomicMax
__device__ __forceinline__ unsigned int enc_f32(float f) {
    unsigned int b = __float_as_uint(f);
    return (b & 0x80000000u) ? ~b : (b | 0x80000000u);
}

__device__ __forceinline__ float dec_f32(unsigned int e) {
    unsigned int b = (e & 0x80000000u) ? (e & 0x7fffffffu) : ~e;
    return __uint_as_float(b);
}

__device__ __forceinline__ void gld_lds16(const void* g, void* l) {
    __builtin_amdgcn_global_load_lds((__attribute__((address_space(1))) void*)g,
                                     (__attribute__((address_space(3))) void*)l,
                                     16, 0, 0);
}

// ---------------------------------------------------------------------------
// Convert fp32 (row-major 4096x512) -> bf16 in MFMA-fragment-swizzled layout:
// subtile = 16 rows x 32 cols; subtile si = (row/16)*16 + (col/32);
// within subtile: lane = (row%16) | (((col%32)/8)<<4), j = col%8
// flat element = si*512 + lane*8 + j   (each lane fragment = 16B contiguous)
// ---------------------------------------------------------------------------
__global__ __launch_bounds__(256) void k_convert(const float* __restrict__ zs,
                                                 const float* __restrict__ zi,
                                                 __hip_bfloat16* __restrict__ outb) {
    int gid = blockIdx.x * 256 + threadIdx.x;   // [0, 2*4096*64)
    int mat = gid >> 18;                        // 0 = zs, 1 = zi
    int t   = gid & 0x3FFFF;
    int si  = t >> 6;
    int L   = t & 63;
    const float* src = mat ? zi : zs;
    int row = ((si >> 4) << 4) | (L & 15);
    int col = ((si & 15) << 5) | (((L >> 4) & 3) << 3);
    const float4* p = (const float4*)(src + (size_t)row * ND + col);
    float4 f0 = p[0];
    float4 f1 = p[1];
    union { __hip_bfloat16 h[8]; bf16x8 v; } u;
    u.h[0] = __float2bfloat16(f0.x);
    u.h[1] = __float2bfloat16(f0.y);
    u.h[2] = __float2bfloat16(f0.z);
    u.h[3] = __float2bfloat16(f0.w);
    u.h[4] = __float2bfloat16(f1.x);
    u.h[5] = __float2bfloat16(f1.y);
    u.h[6] = __float2bfloat16(f1.z);
    u.h[7] = __float2bfloat16(f1.w);
    bf16x8* dst = (bf16x8*)(outb + ((size_t)mat << 21) + ((size_t)si << 9) + (L << 3));
    *dst = u.v;
}

// ---------------------------------------------------------------------------
// fp32 diagonal p[a] = 1 - <z_s[a], z_i[a]>  (one wave per row) + label hist
// ---------------------------------------------------------------------------
__global__ __launch_bounds__(256) void k_diag_hist(const float* __restrict__ zs,
                                                   const float* __restrict__ zi,
                                                   const int* __restrict__ labels,
                                                   float* __restrict__ p_diag,
                                                   int* __restrict__ hist) {
    int w = threadIdx.x >> 6, lane = threadIdx.x & 63;
    int a = blockIdx.x * 4 + w;
    const float4* ps = (const float4*)(zs + (size_t)a * ND + lane * 8);
    const float4* pi = (const float4*)(zi + (size_t)a * ND + lane * 8);
    float4 s0 = ps[0], s1 = ps[1];
    float4 i0 = pi[0], i1 = pi[1];
    float d = s0.x * i0.x + s0.y * i0.y + s0.z * i0.z + s0.w * i0.w
            + s1.x * i1.x + s1.y * i1.y + s1.z * i1.z + s1.w * i1.w;
#pragma unroll
    for (int off = 32; off > 0; off >>= 1) d += __shfl_xor(d, off);
    if (lane == 0) {
        p_diag[a] = 1.0f - d;
        atomicAdd(&hist[labels[a]], 1);
    }
}

// ---------------------------------------------------------------------------
// 128x128 tile GEMM (S = Zs . Zi^T), BK=64, 4 waves, wave tile 64x64 as
// 4x4 of 16x16x32 bf16 MFMA. Epilogue: per-row masked max -> atomicMax.
// ---------------------------------------------------------------------------
__global__ __launch_bounds__(256) void k_gemm_rowmax(const __hip_bfloat16* __restrict__ zsb,
                                                     const __hip_bfloat16* __restrict__ zib,
                                                     const int* __restrict__ labels,
                                                     unsigned int* __restrict__ rowmax) {
    __shared__ __align__(16) unsigned char sA[16384];   // 8 row-sub x 2 k-sub x 1KB
    __shared__ __align__(16) unsigned char sB[16384];
    __shared__ int labA[128];
    __shared__ int labB[128];

    const int tid = threadIdx.x;
    const int bx = blockIdx.x, by = blockIdx.y;

    if (tid < 128) labA[tid] = labels[by * 128 + tid];
    else           labB[tid - 128] = labels[bx * 128 + (tid - 128)];

    const char* gA = (const char*)zsb;
    const char* gB = (const char*)zib;
    const int rb0 = tid >> 7;              // 0/1
    const int rem = (tid & 127) << 4;      // covers kb*1024 + lane*16
    size_t aStat[4], bStat[4];
#pragma unroll
    for (int rd = 0; rd < 4; ++rd) {
        int rb = rd * 2 + rb0;             // local row-block 0..7
        aStat[rd] = ((size_t)(by * 8 + rb) << 14) + rem;   // *16384 bytes (16 subtiles/row-block)
        bStat[rd] = ((size_t)(bx * 8 + rb) << 14) + rem;
    }

    const int w = tid >> 6, lane = tid & 63;
    const int w_m = w >> 1, w_n = w & 1;
    const int fragOff = lane << 4;

    f32x4 acc[4][4];
#pragma unroll
    for (int i = 0; i < 4; ++i)
#pragma unroll
        for (int j = 0; j < 4; ++j)
            acc[i][j] = (f32x4){0.f, 0.f, 0.f, 0.f};

    for (int ks = 0; ks < 8; ++ks) {
        __syncthreads();
#pragma unroll
        for (int rd = 0; rd < 4; ++rd) {
            gld_lds16(gA + aStat[rd] + (size_t)ks * 2048, sA + rd * 4096 + (tid << 4));
            gld_lds16(gB + bStat[rd] + (size_t)ks * 2048, sB + rd * 4096 + (tid << 4));
        }
        __syncthreads();
#pragma unroll
        for (int kb = 0; kb < 2; ++kb) {
            bf16x8 af[4], bfr[4];
#pragma unroll
            for (int ms = 0; ms < 4; ++ms)
                af[ms] = *(const bf16x8*)(sA + (((w_m * 4 + ms) * 2 + kb) << 10) + fragOff);
#pragma unroll
            for (int ns = 0; ns < 4; ++ns)
                bfr[ns] = *(const bf16x8*)(sB + (((w_n * 4 + ns) * 2 + kb) << 10) + fragOff);
#pragma unroll
            for (int ms = 0; ms < 4; ++ms)
#pragma unroll
                for (int ns = 0; ns < 4; ++ns)
                    acc[ms][ns] = __builtin_amdgcn_mfma_f32_16x16x32_bf16(
                        af[ms], bfr[ns], acc[ms][ns], 0, 0, 0);
        }
    }

    // epilogue: C/D layout col = lane&15, row = (lane>>4)*4 + reg
    const int quad = lane >> 4;
    const int lcol = lane & 15;
#pragma unroll
    for (int ms = 0; ms < 4; ++ms) {
        int la[4];
#pragma unroll
        for (int r = 0; r < 4; ++r)
            la[r] = labA[w_m * 64 + ms * 16 + quad * 4 + r];
        float mx[4] = {-3.0e38f, -3.0e38f, -3.0e38f, -3.0e38f};
#pragma unroll
        for (int ns = 0; ns < 4; ++ns) {
            int lb = labB[w_n * 64 + ns * 16 + lcol];
#pragma unroll
            for (int r = 0; r < 4; ++r) {
                float v = acc[ms][ns][r];
                if (la[r] != lb && v > mx[r]) mx[r] = v;
            }
        }
#pragma unroll
        for (int r = 0; r < 4; ++r) {
            float m = mx[r];
            m = fmaxf(m, __shfl_xor(m, 1));
            m = fmaxf(m, __shfl_xor(m, 2));
            m = fmaxf(m, __shfl_xor(m, 4));
            m = fmaxf(m, __shfl_xor(m, 8));
            if (lcol == 0) {
                int rowg = by * 128 + w_m * 64 + ms * 16 + quad * 4 + r;
                atomicMax(&rowmax[rowg], enc_f32(m));
            }
        }
    }
}

// ---------------------------------------------------------------------------
// Finalize: n = 1 - maxdot; per = relu(p - n + margin); masked mean -> out[0]
// ---------------------------------------------------------------------------
__global__ __launch_bounds__(256) void k_finalize(const unsigned int* __restrict__ rowmax,
                                                  const float* __restrict__ p_diag,
                                                  const int* __restrict__ labels,
                                                  const int* __restrict__ hist,
                                                  float* __restrict__ out) {
    int tid = threadIdx.x;
    float sum = 0.0f;
    int cnt = 0;
    for (int a = tid; a < NB; a += 256) {
        bool hn = hist[labels[a]] < NB;
        if (hn) {
            float n = 1.0f - dec_f32(rowmax[a]);
            float per = p_diag[a] - n + MARGIN_F;
            if (per > 0.0f) sum += per;
            cnt++;
        }
    }
#pragma unroll
    for (int off = 32; off > 0; off >>= 1) {
        sum += __shfl_xor(sum, off);
        cnt += __shfl_xor(cnt, off);
    }
    __shared__ float sSum[4];
    __shared__ int sCnt[4];
    int w = tid >> 6, lane = tid & 63;
    if (lane == 0) { sSum[w] = sum; sCnt[w] = cnt; }
    __syncthreads();
    if (tid == 0) {
        float ts = sSum[0] + sSum[1] + sSum[2] + sSum[3];
        int tc = sCnt[0] + sCnt[1] + sCnt[2] + sCnt[3];
        out[0] = (tc > 0) ? ts / (float)tc : 0.0f;
    }
}

extern "C" void kernel_launch(void* const* d_in, const int* in_sizes, int n_in,
                              void* d_out, int out_size, void* d_ws, size_t ws_size,
                              hipStream_t stream) {
    (void)in_sizes; (void)n_in; (void)out_size; (void)ws_size;
    const float* zs = (const float*)d_in[0];
    const float* zi = (const float*)d_in[1];
    const int* labels = (const int*)d_in[2];
    float* out = (float*)d_out;

    char* ws = (char*)d_ws;
    __hip_bfloat16* zb = (__hip_bfloat16*)ws;                       // 8 MB (zs then zi, swizzled)
    unsigned int* rowmax = (unsigned int*)(ws + (8u << 20));        // 16 KB
    int* hist = (int*)(ws + (8u << 20) + 16384);                    // 4 KB (1024 bins)
    float* p_diag = (float*)(ws + (8u << 20) + 16384 + 4096);       // 16 KB

    hipMemsetAsync(rowmax, 0, 16384 + 4096, stream);                // rowmax + hist

    k_convert<<<2048, 256, 0, stream>>>(zs, zi, zb);
    k_diag_hist<<<1024, 256, 0, stream>>>(zs, zi, labels, p_diag, hist);
    dim3 g(32, 32);
    k_gemm_rowmax<<<g, 256, 0, stream>>>(zb, zb + (size_t)NB * ND, labels, rowmax);
    k_finalize<<<1, 256, 0, stream>>>(rowmax, p_diag, labels, hist, out);
}

// Round 2
// 111.138 us; speedup vs baseline: 1.0337x; 1.0337x over previous
//
#include <hip/hip_runtime.h>
#include <hip/hip_bf16.h>

typedef __attribute__((ext_vector_type(8))) short bf16x8;
typedef __attribute__((ext_vector_type(4))) float f32x4;

#define NB 4096
#define ND 512
#define MARGIN_F 0.2f

// order-preserving float -> uint encoding for atomicMax.
// enc(f) == 0 is impossible for finite f (requires bits 0xFFFFFFFF = -NaN),
// so rowmax[a] == 0  <=>  no wave ever found a different-label column in row a.
__device__ __forceinline__ unsigned int enc_f32(float f) {
    unsigned int b = __float_as_uint(f);
    return (b & 0x80000000u) ? ~b : (b | 0x80000000u);
}

__device__ __forceinline__ float dec_f32(unsigned int e) {
    unsigned int b = (e & 0x80000000u) ? (e & 0x7fffffffu) : ~e;
    return __uint_as_float(b);
}

__device__ __forceinline__ void gld_lds16(const void* g, void* l) {
    __builtin_amdgcn_global_load_lds((__attribute__((address_space(1))) void*)g,
                                     (__attribute__((address_space(3))) void*)l,
                                     16, 0, 0);
}

// ---------------------------------------------------------------------------
// Fused prep kernel, grid = 3072 blocks x 256:
//   blocks [0,2048):   fp32 -> bf16 fragment-swizzled convert (both matrices)
//   blocks [2048,3072): fp32 diagonal p[a] = 1 - <zs[a], zi[a]> (wave/row)
//                       + zero 4 rowmax entries per block
// Swizzle: subtile = 16 rows x 32 cols; si = (row/16)*16 + (col/32);
// lane = (row%16) | (((col%32)/8)<<4); flat = si*512 + lane*8 + j.
// ---------------------------------------------------------------------------
__global__ __launch_bounds__(256) void k_prep(const float* __restrict__ zs,
                                              const float* __restrict__ zi,
                                              __hip_bfloat16* __restrict__ outb,
                                              float* __restrict__ p_diag,
                                              unsigned int* __restrict__ rowmax) {
    const int bid = blockIdx.x;
    if (bid < 2048) {
        int gid = bid * 256 + threadIdx.x;   // [0, 2*4096*64)
        int mat = gid >> 18;                 // 0 = zs, 1 = zi
        int t   = gid & 0x3FFFF;
        int si  = t >> 6;
        int L   = t & 63;
        const float* src = mat ? zi : zs;
        int row = ((si >> 4) << 4) | (L & 15);
        int col = ((si & 15) << 5) | (((L >> 4) & 3) << 3);
        const float4* p = (const float4*)(src + (size_t)row * ND + col);
        float4 f0 = p[0];
        float4 f1 = p[1];
        union { __hip_bfloat16 h[8]; bf16x8 v; } u;
        u.h[0] = __float2bfloat16(f0.x);
        u.h[1] = __float2bfloat16(f0.y);
        u.h[2] = __float2bfloat16(f0.z);
        u.h[3] = __float2bfloat16(f0.w);
        u.h[4] = __float2bfloat16(f1.x);
        u.h[5] = __float2bfloat16(f1.y);
        u.h[6] = __float2bfloat16(f1.z);
        u.h[7] = __float2bfloat16(f1.w);
        bf16x8* dst = (bf16x8*)(outb + ((size_t)mat << 21) + ((size_t)si << 9) + (L << 3));
        *dst = u.v;
    } else {
        int db = bid - 2048;                 // 0..1023
        int w = threadIdx.x >> 6, lane = threadIdx.x & 63;
        int a = db * 4 + w;
        const float4* ps = (const float4*)(zs + (size_t)a * ND + lane * 8);
        const float4* pi = (const float4*)(zi + (size_t)a * ND + lane * 8);
        float4 s0 = ps[0], s1 = ps[1];
        float4 i0 = pi[0], i1 = pi[1];
        float d = s0.x * i0.x + s0.y * i0.y + s0.z * i0.z + s0.w * i0.w
                + s1.x * i1.x + s1.y * i1.y + s1.z * i1.z + s1.w * i1.w;
#pragma unroll
        for (int off = 32; off > 0; off >>= 1) d += __shfl_xor(d, off);
        if (lane == 0) p_diag[a] = 1.0f - d;
        if (threadIdx.x < 4) rowmax[db * 4 + threadIdx.x] = 0u;
    }
}

// ---------------------------------------------------------------------------
// 128x128 tile GEMM (S = Zs . Zi^T), BK=64, 4 waves, wave tile 64x64 as
// 4x4 of 16x16x32 bf16 MFMA. Epilogue: per-row masked max -> atomicMax,
// skipped when no different-label column was seen (keeps rowmax==0 sentinel).
// ---------------------------------------------------------------------------
__global__ __launch_bounds__(256) void k_gemm_rowmax(const __hip_bfloat16* __restrict__ zsb,
                                                     const __hip_bfloat16* __restrict__ zib,
                                                     const int* __restrict__ labels,
                                                     unsigned int* __restrict__ rowmax) {
    __shared__ __align__(16) unsigned char sA[16384];   // 8 row-sub x 2 k-sub x 1KB
    __shared__ __align__(16) unsigned char sB[16384];
    __shared__ int labA[128];
    __shared__ int labB[128];

    const int tid = threadIdx.x;
    const int bx = blockIdx.x, by = blockIdx.y;

    if (tid < 128) labA[tid] = labels[by * 128 + tid];
    else           labB[tid - 128] = labels[bx * 128 + (tid - 128)];

    const char* gA = (const char*)zsb;
    const char* gB = (const char*)zib;
    const int rb0 = tid >> 7;              // 0/1
    const int rem = (tid & 127) << 4;      // covers kb*1024 + lane*16
    size_t aStat[4], bStat[4];
#pragma unroll
    for (int rd = 0; rd < 4; ++rd) {
        int rb = rd * 2 + rb0;             // local row-block 0..7
        aStat[rd] = ((size_t)(by * 8 + rb) << 14) + rem;   // *16384 bytes
        bStat[rd] = ((size_t)(bx * 8 + rb) << 14) + rem;
    }

    const int w = tid >> 6, lane = tid & 63;
    const int w_m = w >> 1, w_n = w & 1;
    const int fragOff = lane << 4;

    f32x4 acc[4][4];
#pragma unroll
    for (int i = 0; i < 4; ++i)
#pragma unroll
        for (int j = 0; j < 4; ++j)
            acc[i][j] = (f32x4){0.f, 0.f, 0.f, 0.f};

    for (int ks = 0; ks < 8; ++ks) {
        __syncthreads();
#pragma unroll
        for (int rd = 0; rd < 4; ++rd) {
            gld_lds16(gA + aStat[rd] + (size_t)ks * 2048, sA + rd * 4096 + (tid << 4));
            gld_lds16(gB + bStat[rd] + (size_t)ks * 2048, sB + rd * 4096 + (tid << 4));
        }
        __syncthreads();
#pragma unroll
        for (int kb = 0; kb < 2; ++kb) {
            bf16x8 af[4], bfr[4];
#pragma unroll
            for (int ms = 0; ms < 4; ++ms)
                af[ms] = *(const bf16x8*)(sA + (((w_m * 4 + ms) * 2 + kb) << 10) + fragOff);
#pragma unroll
            for (int ns = 0; ns < 4; ++ns)
                bfr[ns] = *(const bf16x8*)(sB + (((w_n * 4 + ns) * 2 + kb) << 10) + fragOff);
#pragma unroll
            for (int ms = 0; ms < 4; ++ms)
#pragma unroll
                for (int ns = 0; ns < 4; ++ns)
                    acc[ms][ns] = __builtin_amdgcn_mfma_f32_16x16x32_bf16(
                        af[ms], bfr[ns], acc[ms][ns], 0, 0, 0);
        }
    }

    // epilogue: C/D layout col = lane&15, row = (lane>>4)*4 + reg
    const int quad = lane >> 4;
    const int lcol = lane & 15;
#pragma unroll
    for (int ms = 0; ms < 4; ++ms) {
        int la[4];
#pragma unroll
        for (int r = 0; r < 4; ++r)
            la[r] = labA[w_m * 64 + ms * 16 + quad * 4 + r];
        float mx[4] = {-3.0e38f, -3.0e38f, -3.0e38f, -3.0e38f};
#pragma unroll
        for (int ns = 0; ns < 4; ++ns) {
            int lb = labB[w_n * 64 + ns * 16 + lcol];
#pragma unroll
            for (int r = 0; r < 4; ++r) {
                float v = acc[ms][ns][r];
                if (la[r] != lb && v > mx[r]) mx[r] = v;
            }
        }
#pragma unroll
        for (int r = 0; r < 4; ++r) {
            float m = mx[r];
            m = fmaxf(m, __shfl_xor(m, 1));
            m = fmaxf(m, __shfl_xor(m, 2));
            m = fmaxf(m, __shfl_xor(m, 4));
            m = fmaxf(m, __shfl_xor(m, 8));
            // skip if this wave's 16-col slice had no different-label column
            if (lcol == 0 && m > -2.9e38f) {
                int rowg = by * 128 + w_m * 64 + ms * 16 + quad * 4 + r;
                atomicMax(&rowmax[rowg], enc_f32(m));
            }
        }
    }
}

// ---------------------------------------------------------------------------
// Finalize: has_neg = (rowmax != 0); n = 1 - dec(rowmax);
// per = relu(p - n + margin); masked mean -> out[0]
// ---------------------------------------------------------------------------
__global__ __launch_bounds__(256) void k_finalize(const unsigned int* __restrict__ rowmax,
                                                  const float* __restrict__ p_diag,
                                                  float* __restrict__ out) {
    int tid = threadIdx.x;
    float sum = 0.0f;
    int cnt = 0;
    for (int a = tid; a < NB; a += 256) {
        unsigned int e = rowmax[a];
        if (e != 0u) {
            float n = 1.0f - dec_f32(e);
            float per = p_diag[a] - n + MARGIN_F;
            if (per > 0.0f) sum += per;
            cnt++;
        }
    }
#pragma unroll
    for (int off = 32; off > 0; off >>= 1) {
        sum += __shfl_xor(sum, off);
        cnt += __shfl_xor(cnt, off);
    }
    __shared__ float sSum[4];
    __shared__ int sCnt[4];
    int w = tid >> 6, lane = tid & 63;
    if (lane == 0) { sSum[w] = sum; sCnt[w] = cnt; }
    __syncthreads();
    if (tid == 0) {
        float ts = sSum[0] + sSum[1] + sSum[2] + sSum[3];
        int tc = sCnt[0] + sCnt[1] + sCnt[2] + sCnt[3];
        out[0] = (tc > 0) ? ts / (float)tc : 0.0f;
    }
}

extern "C" void kernel_launch(void* const* d_in, const int* in_sizes, int n_in,
                              void* d_out, int out_size, void* d_ws, size_t ws_size,
                              hipStream_t stream) {
    (void)in_sizes; (void)n_in; (void)out_size; (void)ws_size;
    const float* zs = (const float*)d_in[0];
    const float* zi = (const float*)d_in[1];
    const int* labels = (const int*)d_in[2];
    float* out = (float*)d_out;

    char* ws = (char*)d_ws;
    __hip_bfloat16* zb = (__hip_bfloat16*)ws;                       // 8 MB (zs then zi, swizzled)
    unsigned int* rowmax = (unsigned int*)(ws + (8u << 20));        // 16 KB
    float* p_diag = (float*)(ws + (8u << 20) + 16384);              // 16 KB

    k_prep<<<3072, 256, 0, stream>>>(zs, zi, zb, p_diag, rowmax);
    dim3 g(32, 32);
    k_gemm_rowmax<<<g, 256, 0, stream>>>(zb, zb + (size_t)NB * ND, labels, rowmax);
    k_finalize<<<1, 256, 0, stream>>>(rowmax, p_diag, out);
}

// Round 3
// 104.109 us; speedup vs baseline: 1.1035x; 1.0675x over previous
//
#include <hip/hip_runtime.h>
#include <hip/hip_bf16.h>

typedef __attribute__((ext_vector_type(8))) short bf16x8;
typedef __attribute__((ext_vector_type(4))) float f32x4;

#define NB 4096
#define ND 512
#define MARGIN_F 0.2f

// order-preserving float -> uint encoding for atomicMax.
// enc(f) == 0 is impossible for finite f, so rowmax[a] == 0  <=>
// no wave ever found a different-label column in row a (has_neg == false).
__device__ __forceinline__ unsigned int enc_f32(float f) {
    unsigned int b = __float_as_uint(f);
    return (b & 0x80000000u) ? ~b : (b | 0x80000000u);
}

__device__ __forceinline__ float dec_f32(unsigned int e) {
    unsigned int b = (e & 0x80000000u) ? (e & 0x7fffffffu) : ~e;
    return __uint_as_float(b);
}

__device__ __forceinline__ void gld_lds16(const void* g, void* l) {
    __builtin_amdgcn_global_load_lds((__attribute__((address_space(1))) void*)g,
                                     (__attribute__((address_space(3))) void*)l,
                                     16, 0, 0);
}

// ---------------------------------------------------------------------------
// Prep: fp32 -> bf16 fragment-swizzled convert (both matrices), grid 2048.
// Blocks [0,16) additionally zero the 4096-entry rowmax array.
// Swizzle: subtile = 16 rows x 32 cols; si = (row/16)*16 + (col/32);
// lane = (row%16) | (((col%32)/8)<<4); flat = si*512 + lane*8 + j.
// ---------------------------------------------------------------------------
__global__ __launch_bounds__(256) void k_prep(const float* __restrict__ zs,
                                              const float* __restrict__ zi,
                                              __hip_bfloat16* __restrict__ outb,
                                              unsigned int* __restrict__ rowmax) {
    const int bid = blockIdx.x;
    if (bid < 16) rowmax[bid * 256 + threadIdx.x] = 0u;

    int gid = bid * 256 + threadIdx.x;   // [0, 2*4096*64)
    int mat = gid >> 18;                 // 0 = zs, 1 = zi
    int t   = gid & 0x3FFFF;
    int si  = t >> 6;
    int L   = t & 63;
    const float* src = mat ? zi : zs;
    int row = ((si >> 4) << 4) | (L & 15);
    int col = ((si & 15) << 5) | (((L >> 4) & 3) << 3);
    const float4* p = (const float4*)(src + (size_t)row * ND + col);
    float4 f0 = p[0];
    float4 f1 = p[1];
    union { __hip_bfloat16 h[8]; bf16x8 v; } u;
    u.h[0] = __float2bfloat16(f0.x);
    u.h[1] = __float2bfloat16(f0.y);
    u.h[2] = __float2bfloat16(f0.z);
    u.h[3] = __float2bfloat16(f0.w);
    u.h[4] = __float2bfloat16(f1.x);
    u.h[5] = __float2bfloat16(f1.y);
    u.h[6] = __float2bfloat16(f1.z);
    u.h[7] = __float2bfloat16(f1.w);
    bf16x8* dst = (bf16x8*)(outb + ((size_t)mat << 21) + ((size_t)si << 9) + (L << 3));
    *dst = u.v;
}

// ---------------------------------------------------------------------------
// 128x128 tile GEMM (S = Zs . Zi^T), BK=64, 4 waves, wave tile 64x64 as
// 4x4 of 16x16x32 bf16 MFMA. Epilogue: per-row masked max -> atomicMax
// (skipped while the -3e38 sentinel survives => rowmax==0 means no negative).
// Diagonal blocks (bx==by) also extract p_diag[a] = 1 - S[a][a].
// ---------------------------------------------------------------------------
__global__ __launch_bounds__(256) void k_gemm_rowmax(const __hip_bfloat16* __restrict__ zsb,
                                                     const __hip_bfloat16* __restrict__ zib,
                                                     const int* __restrict__ labels,
                                                     unsigned int* __restrict__ rowmax,
                                                     float* __restrict__ p_diag) {
    __shared__ __align__(16) unsigned char sA[16384];   // 8 row-sub x 2 k-sub x 1KB
    __shared__ __align__(16) unsigned char sB[16384];
    __shared__ int labA[128];
    __shared__ int labB[128];

    const int tid = threadIdx.x;
    const int bx = blockIdx.x, by = blockIdx.y;

    if (tid < 128) labA[tid] = labels[by * 128 + tid];
    else           labB[tid - 128] = labels[bx * 128 + (tid - 128)];

    const char* gA = (const char*)zsb;
    const char* gB = (const char*)zib;
    const int rb0 = tid >> 7;              // 0/1
    const int rem = (tid & 127) << 4;      // covers kb*1024 + lane*16
    size_t aStat[4], bStat[4];
#pragma unroll
    for (int rd = 0; rd < 4; ++rd) {
        int rb = rd * 2 + rb0;             // local row-block 0..7
        aStat[rd] = ((size_t)(by * 8 + rb) << 14) + rem;   // *16384 bytes
        bStat[rd] = ((size_t)(bx * 8 + rb) << 14) + rem;
    }

    const int w = tid >> 6, lane = tid & 63;
    const int w_m = w >> 1, w_n = w & 1;
    const int fragOff = lane << 4;

    f32x4 acc[4][4];
#pragma unroll
    for (int i = 0; i < 4; ++i)
#pragma unroll
        for (int j = 0; j < 4; ++j)
            acc[i][j] = (f32x4){0.f, 0.f, 0.f, 0.f};

    for (int ks = 0; ks < 8; ++ks) {
        __syncthreads();
#pragma unroll
        for (int rd = 0; rd < 4; ++rd) {
            gld_lds16(gA + aStat[rd] + (size_t)ks * 2048, sA + rd * 4096 + (tid << 4));
            gld_lds16(gB + bStat[rd] + (size_t)ks * 2048, sB + rd * 4096 + (tid << 4));
        }
        __syncthreads();
#pragma unroll
        for (int kb = 0; kb < 2; ++kb) {
            bf16x8 af[4], bfr[4];
#pragma unroll
            for (int ms = 0; ms < 4; ++ms)
                af[ms] = *(const bf16x8*)(sA + (((w_m * 4 + ms) * 2 + kb) << 10) + fragOff);
#pragma unroll
            for (int ns = 0; ns < 4; ++ns)
                bfr[ns] = *(const bf16x8*)(sB + (((w_n * 4 + ns) * 2 + kb) << 10) + fragOff);
#pragma unroll
            for (int ms = 0; ms < 4; ++ms)
#pragma unroll
                for (int ns = 0; ns < 4; ++ns)
                    acc[ms][ns] = __builtin_amdgcn_mfma_f32_16x16x32_bf16(
                        af[ms], bfr[ns], acc[ms][ns], 0, 0, 0);
        }
    }

    // epilogue: C/D layout col = lane&15, row = (lane>>4)*4 + reg
    const int quad = lane >> 4;
    const int lcol = lane & 15;

    int lb[4];
#pragma unroll
    for (int ns = 0; ns < 4; ++ns)
        lb[ns] = labB[w_n * 64 + ns * 16 + lcol];

#pragma unroll
    for (int ms = 0; ms < 4; ++ms) {
        int la[4];
#pragma unroll
        for (int r = 0; r < 4; ++r)
            la[r] = labA[w_m * 64 + ms * 16 + quad * 4 + r];
        float mx[4] = {-3.0e38f, -3.0e38f, -3.0e38f, -3.0e38f};
#pragma unroll
        for (int ns = 0; ns < 4; ++ns) {
#pragma unroll
            for (int r = 0; r < 4; ++r) {
                float v = acc[ms][ns][r];
                if (la[r] != lb[ns] && v > mx[r]) mx[r] = v;
            }
        }
#pragma unroll
        for (int r = 0; r < 4; ++r) {
            float m = mx[r];
            m = fmaxf(m, __shfl_xor(m, 1));
            m = fmaxf(m, __shfl_xor(m, 2));
            m = fmaxf(m, __shfl_xor(m, 4));
            m = fmaxf(m, __shfl_xor(m, 8));
            // skip if this wave's 16-col slice had no different-label column
            if (lcol == 0 && m > -2.9e38f) {
                int rowg = by * 128 + w_m * 64 + ms * 16 + quad * 4 + r;
                atomicMax(&rowmax[rowg], enc_f32(m));
            }
        }
    }

    // diagonal blocks: extract p[a] = 1 - S[a][a].
    // Within-block diagonal lives where w_m==w_n, ns==ms, lcol == quad*4+r.
    if (bx == by && w_m == w_n) {
        int r = lcol - quad * 4;
        if (r >= 0 && r < 4) {
#pragma unroll
            for (int ms = 0; ms < 4; ++ms) {
                int rowg = by * 128 + w_m * 64 + ms * 16 + lcol;
                p_diag[rowg] = 1.0f - acc[ms][ms][r];
            }
        }
    }
}

// ---------------------------------------------------------------------------
// Finalize: has_neg = (rowmax != 0); n = 1 - dec(rowmax);
// per = relu(p - n + margin); masked mean -> out[0]
// ---------------------------------------------------------------------------
__global__ __launch_bounds__(1024) void k_finalize(const unsigned int* __restrict__ rowmax,
                                                   const float* __restrict__ p_diag,
                                                   float* __restrict__ out) {
    int tid = threadIdx.x;
    float sum = 0.0f;
    int cnt = 0;
#pragma unroll
    for (int it = 0; it < 4; ++it) {
        int a = tid + it * 1024;
        unsigned int e = rowmax[a];
        if (e != 0u) {
            float n = 1.0f - dec_f32(e);
            float per = p_diag[a] - n + MARGIN_F;
            if (per > 0.0f) sum += per;
            cnt++;
        }
    }
#pragma unroll
    for (int off = 32; off > 0; off >>= 1) {
        sum += __shfl_xor(sum, off);
        cnt += __shfl_xor(cnt, off);
    }
    __shared__ float sSum[16];
    __shared__ int sCnt[16];
    int w = tid >> 6, lane = tid & 63;
    if (lane == 0) { sSum[w] = sum; sCnt[w] = cnt; }
    __syncthreads();
    if (tid == 0) {
        float ts = 0.0f;
        int tc = 0;
#pragma unroll
        for (int i = 0; i < 16; ++i) { ts += sSum[i]; tc += sCnt[i]; }
        out[0] = (tc > 0) ? ts / (float)tc : 0.0f;
    }
}

extern "C" void kernel_launch(void* const* d_in, const int* in_sizes, int n_in,
                              void* d_out, int out_size, void* d_ws, size_t ws_size,
                              hipStream_t stream) {
    (void)in_sizes; (void)n_in; (void)out_size; (void)ws_size;
    const float* zs = (const float*)d_in[0];
    const float* zi = (const float*)d_in[1];
    const int* labels = (const int*)d_in[2];
    float* out = (float*)d_out;

    char* ws = (char*)d_ws;
    __hip_bfloat16* zb = (__hip_bfloat16*)ws;                       // 8 MB (zs then zi, swizzled)
    unsigned int* rowmax = (unsigned int*)(ws + (8u << 20));        // 16 KB
    float* p_diag = (float*)(ws + (8u << 20) + 16384);              // 16 KB

    k_prep<<<2048, 256, 0, stream>>>(zs, zi, zb, rowmax);
    dim3 g(32, 32);
    k_gemm_rowmax<<<g, 256, 0, stream>>>(zb, zb + (size_t)NB * ND, labels, rowmax, p_diag);
    k_finalize<<<1, 1024, 0, stream>>>(rowmax, p_diag, out);
}